// Round 3
// baseline (70494.434 us; speedup 1.0000x reference)
//
#include <hip/hip_runtime.h>

typedef _Float16 h16;
typedef _Float16 half8 __attribute__((ext_vector_type(8)));
typedef float f32x4 __attribute__((ext_vector_type(4)));

#define NEGV -1000000000.0f
#define MFMA16(a,b,c) __builtin_amdgcn_mfma_f32_16x16x32_f16(a,b,c,0,0,0)

struct Params {
  const float *memory, *dec_in; const int *memlen;
  const float *w1, *w2;
  const float *awih, *awhh, *abih, *abhh;
  const float *qw, *mw, *vw, *lcw, *ldw;
  const float *dwih, *dwhh, *dbih, *dbhh;
  const float *pw, *pb, *gw, *gb;
  float *out, *ws;
};

// ---- ws layout ----
// f16 arrays: offsets in HALFS
constexpr long long XALLF_H = 0;          // 400*32*256  xallf[t][b][256]
constexpr long long PMH_H   = 3276800;    // 32*128*384  pm[b][a][t]
constexpr long long PLB_H   = 4849664;    // 32*128*384  plbT[b][a][t]  (TRANSPOSED)
constexpr long long AWIHF_H = 6422528;    // 4096*768
constexpr long long AWHHF_H = 9568256;    // 4096*1024
constexpr long long DWIHF_H = 13762560;   // 4096*1536
constexpr long long DWHHF_H = 20054016;   // 4096*1024
constexpr long long LCWF_H  = 24248320;   // 32*64 (padded conv wts, f-major)
constexpr long long LDWF_H  = 24250368;   // 128*32 (a-major)
constexpr long long AHF_H   = 24254464;   // 2 * 32*1024 (double buffered)
constexpr long long DHF_H   = 24320000;   // 32*1024
constexpr long long CTXF_H  = 24352768;   // 32*512
// fp32 arrays: offsets in FLOATS
constexpr long long ZERO_F0 = 12127232;   // zero region start (covers AHF..DPART)
constexpr long long AC_F    = 12184576;   // 32*1024
constexpr long long DC_F    = 12217344;   // 32*1024
constexpr long long AW_F    = 12250112;   // 32*384
constexpr long long AWC_F   = 12262400;   // 32*384
constexpr long long DPART_F = 12274688;   // 32*4096
constexpr long long BAR_F   = 12405760;   // 512 uints
constexpr int  ZERO_LEN = 278528;
constexpr unsigned NBLK = 512;
// out layout
constexpr long long GATE0  = 1024000;
constexpr long long ALIGN0 = 1036800;

union SMem {
  float pmstage[12][512];                                     // 24.6 KB
  struct { float x[5][80]; float l1[5][256]; } pre;
  struct { float red[4][2][16][17]; } g;                      // 8.7 KB
  struct { float awseg[2][128]; h16 im2[96][72]; h16 locT[96][32];
           h16 pT[128][100]; } ploc;                          // 46.6 KB (max)
  struct { float ah[1024]; float pq[128]; float pqp[2][128]; float vv[128];
           float e[384]; float w[384]; float red[16];
           float ctxred[4][512]; } row;                       // 17.6 KB
  struct { float hc[1536]; float mp[80][2]; float gacc; } mel;
};

__device__ __forceinline__ float sigf(float x){ return 1.0f/(1.0f+__expf(-x)); }
__device__ __forceinline__ float tanhfast(float x){ float e2 = __expf(2.0f*x); return 1.0f - 2.0f/(e2+1.0f); }

// ---- agent-scope (cross-XCD coherent, cache-bypassing) accessors ----
__device__ __forceinline__ float aldf(const float* p){
  return __hip_atomic_load(p, __ATOMIC_RELAXED, __HIP_MEMORY_SCOPE_AGENT);
}
__device__ __forceinline__ void astf(float* p, float v){
  __hip_atomic_store(p, v, __ATOMIC_RELAXED, __HIP_MEMORY_SCOPE_AGENT);
}
__device__ __forceinline__ unsigned long long aldu64(const h16* p){
  return __hip_atomic_load((const unsigned long long*)p, __ATOMIC_RELAXED, __HIP_MEMORY_SCOPE_AGENT);
}
__device__ __forceinline__ half8 ald16(const h16* p){
  union { unsigned long long q[2]; half8 v; } u;
  u.q[0] = __hip_atomic_load((const unsigned long long*)p,     __ATOMIC_RELAXED, __HIP_MEMORY_SCOPE_AGENT);
  u.q[1] = __hip_atomic_load(((const unsigned long long*)p)+1, __ATOMIC_RELAXED, __HIP_MEMORY_SCOPE_AGENT);
  return u.v;
}
__device__ __forceinline__ void asth(h16* p, float v){
  union { h16 h; unsigned short s; } u; u.h = (h16)v;
  __hip_atomic_store((unsigned short*)p, u.s, __ATOMIC_RELAXED, __HIP_MEMORY_SCOPE_AGENT);
}
__device__ __forceinline__ void astu64(unsigned long long* p, unsigned long long v){
  __hip_atomic_store(p, v, __ATOMIC_RELAXED, __HIP_MEMORY_SCOPE_AGENT);
}
__device__ __forceinline__ unsigned short aldu16(const unsigned short* p){
  return __hip_atomic_load(p, __ATOMIC_RELAXED, __HIP_MEMORY_SCOPE_AGENT);
}

// software grid barrier (round-0 proven design); full=true adds release/acquire
// cache maintenance. Flat poll-sum of 8 counter lines: detection latency is one
// poll period (~1us) after the last arrival's add lands.
__device__ __forceinline__ void gbar(unsigned* cnts, unsigned ep, bool full){
  __syncthreads();
  if (threadIdx.x == 0){
    if (full) __threadfence();
    __hip_atomic_fetch_add(&cnts[(blockIdx.x & 7)*64], 1u, __ATOMIC_RELEASE, __HIP_MEMORY_SCOPE_AGENT);
    const unsigned tgt = ep*NBLK;
    for (;;){
      unsigned s = 0;
      #pragma unroll
      for (int i = 0; i < 8; ++i)
        s += __hip_atomic_load(&cnts[i*64], __ATOMIC_RELAXED, __HIP_MEMORY_SCOPE_AGENT);
      if (s >= tgt) break;
      __builtin_amdgcn_s_sleep(4);
    }
    if (full) __threadfence();
  }
  __syncthreads();
}

__global__ void init_kernel(float* ws){
  unsigned* c = (unsigned*)(ws + BAR_F);
  if (threadIdx.x < 512) c[threadIdx.x] = 0u;
}

__global__ __launch_bounds__(256, 2)
void decoder_kernel(Params P){
  __shared__ SMem sm;
  const int tid = threadIdx.x;
  const int bid = blockIdx.x;
  float* ws = P.ws;
  h16*   wsh = (h16*)ws;
  unsigned* bar = (unsigned*)(ws + BAR_F);
  unsigned ep = 0;

  const int lane = tid & 63, wv = tid >> 6;
  const int i16 = lane & 15, q = lane >> 4;

  // ============== PROLOGUE ==============
  {
    const long long gtid = (long long)bid*256 + tid;
    // zero state region
    for (long long i = gtid; i < ZERO_LEN; i += 131072) ws[ZERO_F0 + i] = 0.f;
    // weight f16 conversion
    for (long long i = gtid; i < 3145728; i += 131072) wsh[AWIHF_H+i] = (h16)P.awih[i];
    for (long long i = gtid; i < 4194304; i += 131072) wsh[AWHHF_H+i] = (h16)P.awhh[i];
    for (long long i = gtid; i < 6291456; i += 131072) wsh[DWIHF_H+i] = (h16)P.dwih[i];
    for (long long i = gtid; i < 4194304; i += 131072) wsh[DWHHF_H+i] = (h16)P.dwhh[i];
    for (long long i = gtid; i < 2048; i += 131072){
      int f = (int)(i >> 6), kk = (int)(i & 63), ch = kk >> 5, k = kk & 31;
      wsh[LCWF_H+i] = (k < 31) ? (h16)P.lcw[f*62 + ch*31 + k] : (h16)0.f;
    }
    for (long long i = gtid; i < 4096; i += 131072) wsh[LDWF_H+i] = (h16)P.ldw[i];
  }
  // processed_memory -> PMH (f16)
  {
    const int b = bid >> 4, part = bid & 15;
    for (int sub = 0; sub < 2; ++sub){
      const int t0 = part*24 + sub*12;
      __syncthreads();
      for (int i = tid; i < 1536; i += 256){
        int row = i >> 7, c4 = (i & 127) << 2;
        *reinterpret_cast<float4*>(&sm.pmstage[row][c4]) =
          *reinterpret_cast<const float4*>(P.memory + ((long long)(b*384 + t0 + row))*512 + c4);
      }
      __syncthreads();
      const int a = tid & 127, th = tid >> 7;
      float acc[6] = {0,0,0,0,0,0};
      const float* mwr = P.mw + (long long)a*512;
      for (int e = 0; e < 512; ++e){
        float wvv = mwr[e];
        #pragma unroll
        for (int jj = 0; jj < 6; ++jj) acc[jj] += wvv*sm.pmstage[th*6+jj][e];
      }
      #pragma unroll
      for (int jj = 0; jj < 6; ++jj)
        wsh[PMH_H + ((long long)b*128 + a)*384 + t0 + th*6 + jj] = (h16)acc[jj];
    }
  }
  // prenet -> XALLF (f16)
  {
    for (int batch = 0; batch < 5; ++batch){
      const int pbase = bid*25 + batch*5;
      __syncthreads();
      for (int i = tid; i < 400; i += 256){
        int j = i/80, m = i%80;
        int p = pbase + j; int tq = p >> 5, bb = p & 31;
        float v = 0.f;
        if (tq > 0) v = P.dec_in[((long long)bb*80 + m)*400 + (tq-1)];
        sm.pre.x[j][m] = v;
      }
      __syncthreads();
      {
        float acc[5] = {0,0,0,0,0};
        const float* w1r = P.w1 + (long long)tid*80;
        for (int m = 0; m < 80; ++m){
          float wvv = w1r[m];
          #pragma unroll
          for (int j = 0; j < 5; ++j) acc[j] += wvv*sm.pre.x[j][m];
        }
        __syncthreads();
        #pragma unroll
        for (int j = 0; j < 5; ++j) sm.pre.l1[j][tid] = fmaxf(acc[j], 0.f);
      }
      __syncthreads();
      {
        float acc[5] = {0,0,0,0,0};
        const float* w2r = P.w2 + (long long)tid*256;
        for (int pp = 0; pp < 256; ++pp){
          float wvv = w2r[pp];
          #pragma unroll
          for (int j = 0; j < 5; ++j) acc[j] += wvv*sm.pre.l1[j][pp];
        }
        #pragma unroll
        for (int j = 0; j < 5; ++j){
          int p = pbase + j; int tq = p >> 5, bb = p & 31;
          wsh[XALLF_H + ((long long)tq*32 + bb)*256 + tid] = (h16)fmaxf(acc[j], 0.f);
        }
      }
    }
  }
  gbar(bar, ++ep, true);   // full fence once: weights/PMH/XALLF now visible + cached

  // ============== MAIN LOOP ==============
  for (int t = 0; t <= 400; ++t){
    const int cur = t & 1, prv = (t+1) & 1;

    // ---------- PHASE A ----------
    if (bid < 256){
      // att-LSTM: 4 units/block via MFMA, waves split K (56 steps = 4x14).
      // A-tiles (the L2-missing weight stream) prefetched into registers:
      // 14 x 16B in flight per wave (Little's law: was ~4, latency-bound).
      if (t < 400){
        const int u0 = bid*4;
        const int n = ((i16 >> 2)*1024) + u0 + (i16 & 3);   // gate-gathered row
        f32x4 acc0 = {0,0,0,0}, acc1 = {0,0,0,0};
        const long long prvO = (long long)prv*32768;
        half8 Areg[14];
        #pragma unroll
        for (int i = 0; i < 14; ++i){
          const int k0 = (wv*14 + i)*32;
          const h16* pA = (k0 < 768) ? wsh + AWIHF_H + (long long)n*768 + k0 + q*8
                                     : wsh + AWHHF_H + (long long)n*1024 + (k0-768) + q*8;
          Areg[i] = *(const half8*)pA;
        }
        #pragma unroll
        for (int i = 0; i < 14; ++i){
          const int k0 = (wv*14 + i)*32;
          half8 B0, B1;
          if (k0 < 256){
            B0 = *(const half8*)(wsh + XALLF_H + ((long long)t*32 + i16)*256 + k0 + q*8);
            B1 = *(const half8*)(wsh + XALLF_H + ((long long)t*32 + 16 + i16)*256 + k0 + q*8);
          } else if (k0 < 768){
            B0 = ald16(wsh + CTXF_H + i16*512 + (k0-256) + q*8);
            B1 = ald16(wsh + CTXF_H + (16+i16)*512 + (k0-256) + q*8);
          } else {
            B0 = ald16(wsh + AHF_H + prvO + i16*1024 + (k0-768) + q*8);
            B1 = ald16(wsh + AHF_H + prvO + (16+i16)*1024 + (k0-768) + q*8);
          }
          acc0 = MFMA16(Areg[i], B0, acc0);
          acc1 = MFMA16(Areg[i], B1, acc1);
        }
        #pragma unroll
        for (int r = 0; r < 4; ++r){
          sm.g.red[wv][0][q*4+r][i16] = acc0[r];
          sm.g.red[wv][1][q*4+r][i16] = acc1[r];
        }
        __syncthreads();
        if (tid < 128){
          const int uu = tid >> 5, b = tid & 31;
          const int bt = b >> 4, c = b & 15;
          float g4[4];
          #pragma unroll
          for (int g = 0; g < 4; ++g){
            const int tr = g*4 + uu;
            float v = sm.g.red[0][bt][tr][c] + sm.g.red[1][bt][tr][c]
                    + sm.g.red[2][bt][tr][c] + sm.g.red[3][bt][tr][c];
            const int ng = g*1024 + u0 + uu;
            g4[g] = v + P.abih[ng] + P.abhh[ng];
          }
          const long long idx = (long long)b*1024 + u0 + uu;
          float c2 = sigf(g4[1])*ws[AC_F + idx] + sigf(g4[0])*tanhfast(g4[2]);
          ws[AC_F + idx] = c2;
          asth(wsh + AHF_H + (long long)cur*32768 + idx, sigf(g4[3])*tanhfast(c2));
        }
      }
    } else if (bid < 384){
      // loc conv + dense via MFMA -> plbT f16 [b][a][t]  (consumer-coalesced)
      if (t < 400){
        const int pb = bid - 256, b = pb >> 2, tbase = (pb & 3)*96;
        for (int i = tid; i < 252; i += 256){
          int ch = i / 126, ix = i % 126;
          int pos = tbase - 15 + ix;
          float v = 0.f;
          if (pos >= 0 && pos < 384)
            v = aldf(ws + (ch ? AWC_F : AW_F) + b*384 + pos);
          sm.ploc.awseg[ch][ix] = v;
        }
        __syncthreads();
        for (int i = tid; i < 96*64; i += 256){
          int tt = i >> 6, kk = i & 63, ch = kk >> 5, k = kk & 31;
          sm.ploc.im2[tt][kk] = (k < 31) ? (h16)sm.ploc.awseg[ch][tt + k] : (h16)0.f;
        }
        __syncthreads();
        // conv: out[t'][f] = sum_k im2[t'][k] * lcwf[f][k]; 12 tiles, 3/wave
        #pragma unroll
        for (int p = 0; p < 3; ++p){
          int tile = wv + p*4;
          int tT = tile % 6, tF = tile / 6;
          f32x4 a = {0,0,0,0};
          #pragma unroll
          for (int ks = 0; ks < 2; ++ks){
            half8 A = *(const half8*)&sm.ploc.im2[tT*16 + i16][ks*32 + q*8];
            half8 B = *(const half8*)(wsh + LCWF_H + (tF*16 + i16)*64 + ks*32 + q*8);
            a = MFMA16(A, B, a);
          }
          #pragma unroll
          for (int r = 0; r < 4; ++r)
            sm.ploc.locT[tT*16 + q*4 + r][tF*16 + i16] = (h16)a[r];
        }
        __syncthreads();
        // dense: pT[a][t'] = pm + sum_f locT[t'][f]*ldw[a][f]; 48 tiles, 12/wave
        #pragma unroll
        for (int p = 0; p < 12; ++p){
          int tile = wv + p*4;
          int tT = tile % 6, tA = tile / 6;
          half8 A = *(const half8*)&sm.ploc.locT[tT*16 + i16][q*8];
          half8 B = *(const half8*)(wsh + LDWF_H + (tA*16 + i16)*32 + q*8);
          f32x4 a = {0,0,0,0};
          a = MFMA16(A, B, a);
          int aa = tA*16 + i16;
          union { unsigned long long u; h16 h[4]; } pmu;
          pmu.u = *(const unsigned long long*)
              (wsh + PMH_H + ((long long)b*128 + aa)*384 + tbase + tT*16 + q*4);
          #pragma unroll
          for (int r = 0; r < 4; ++r)
            sm.ploc.pT[aa][tT*16 + q*4 + r] = (h16)(a[r] + (float)pmu.h[r]);
        }
        __syncthreads();
        // write-out: plbT[b][a][tbase..tbase+95], 8B coalesced atomic stores
        {
          unsigned long long* plbq = (unsigned long long*)(wsh + PLB_H);
          for (int i = tid; i < 3072; i += 256){
            int a2 = i/24, tp = i - a2*24;
            unsigned long long v = *reinterpret_cast<const unsigned long long*>(&sm.ploc.pT[a2][4*tp]);
            astu64(plbq + ((((long long)b*128 + a2)*384 + tbase) >> 2) + tp, v);
          }
        }
      }
    } else {
      // dec-LSTM ctx-part (K=512) + cell for step t-1: 8 units/block.
      // A-tiles prefetched: 8 x 16B in flight per wave.
      if (t >= 1){
        const int u0 = (bid-384)*8;
        const int jt = wv & 1, kh = wv >> 1;
        const int n = ((i16 >> 2)*1024) + u0 + jt*4 + (i16 & 3);
        f32x4 acc0 = {0,0,0,0}, acc1 = {0,0,0,0};
        half8 Areg[8];
        #pragma unroll
        for (int i = 0; i < 8; ++i){
          const int k0 = (kh*8 + i)*32;
          Areg[i] = *(const half8*)(wsh + DWIHF_H + (long long)n*1536 + 1024 + k0 + q*8);
        }
        #pragma unroll
        for (int i = 0; i < 8; ++i){
          const int k0 = (kh*8 + i)*32;
          half8 B0 = ald16(wsh + CTXF_H + i16*512 + k0 + q*8);
          half8 B1 = ald16(wsh + CTXF_H + (16+i16)*512 + k0 + q*8);
          acc0 = MFMA16(Areg[i], B0, acc0);
          acc1 = MFMA16(Areg[i], B1, acc1);
        }
        #pragma unroll
        for (int r = 0; r < 4; ++r){
          sm.g.red[wv][0][q*4+r][i16] = acc0[r];
          sm.g.red[wv][1][q*4+r][i16] = acc1[r];
        }
        __syncthreads();
        {
          const int uu8 = tid >> 5, b = tid & 31;
          const int j2 = uu8 >> 2, uu = uu8 & 3;
          const int bt = b >> 4, c = b & 15;
          const int unit = u0 + j2*4 + uu;
          float g4[4];
          #pragma unroll
          for (int g = 0; g < 4; ++g){
            const int tr = g*4 + uu;
            const int ng = g*1024 + unit;
            g4[g] = sm.g.red[j2][bt][tr][c] + sm.g.red[j2+2][bt][tr][c]
                  + aldf(ws + DPART_F + (long long)b*4096 + ng)
                  + P.dbih[ng] + P.dbhh[ng];
          }
          const long long idx = (long long)b*1024 + unit;
          float c2 = sigf(g4[1])*ws[DC_F + idx] + sigf(g4[0])*tanhfast(g4[2]);
          ws[DC_F + idx] = c2;
          asth(wsh + DHF_H + idx, sigf(g4[3])*tanhfast(c2));
        }
      }
    }
    gbar(bar, ++ep, false);

    // ---------- PHASE B ----------
    if (bid < 32){
      // attention: pq, energies, softmax, ctx, aw/awc, alignments
      if (t < 400){
        const int b = bid;
        const int len = P.memlen[b];
        {
          union { unsigned long long u; h16 h[4]; } hu;
          hu.u = aldu64(wsh + AHF_H + (long long)cur*32768 + b*1024 + tid*4);
          #pragma unroll
          for (int j = 0; j < 4; ++j) sm.row.ah[tid*4+j] = (float)hu.h[j];
        }
        if (tid < 128) sm.row.vv[tid] = P.vw[tid];
        __syncthreads();
        {
          const int a = tid & 127, kh2 = tid >> 7;
          const float* qr  = P.qw + (long long)a*1024 + kh2*512;
          const float* ahs = &sm.row.ah[kh2*512];
          float acc = 0.f;
          for (int k = 0; k < 512; k += 4){
            float4 wq = *reinterpret_cast<const float4*>(qr + k);
            acc += wq.x*ahs[k] + wq.y*ahs[k+1] + wq.z*ahs[k+2] + wq.w*ahs[k+3];
          }
          sm.row.pqp[kh2][a] = acc;
        }
        __syncthreads();
        if (tid < 128) sm.row.pq[tid] = sm.row.pqp[0][tid] + sm.row.pqp[1][tid];
        __syncthreads();
        // energies from plbT[b][a][t]: lane=tt -> 2B coalesced loads, deep unroll
        for (int pass = 0; pass < 2; ++pass){
          const int tt = tid + pass*256;
          if (tt < 384){
            float acc;
            if (tt < len){
              acc = 0.f;
              const unsigned short* pa = (const unsigned short*)(wsh + PLB_H)
                                       + (long long)b*49152 + tt;
              #pragma unroll 16
              for (int a0 = 0; a0 < 128; ++a0){
                unsigned short hv = aldu16(pa + a0*384);
                union { unsigned short s; h16 h; } uu; uu.s = hv;
                acc += sm.row.vv[a0]*tanhfast(sm.row.pq[a0] + (float)uu.h);
              }
            } else acc = NEGV;
            sm.row.e[tt] = acc;
          }
        }
        __syncthreads();
        float m = NEGV;
        for (int tt = tid; tt < 384; tt += 256) m = fmaxf(m, sm.row.e[tt]);
        for (int o = 32; o; o >>= 1) m = fmaxf(m, __shfl_xor(m, o, 64));
        if ((tid & 63) == 0) sm.row.red[tid >> 6] = m;
        __syncthreads();
        const float mx = fmaxf(fmaxf(sm.row.red[0], sm.row.red[1]),
                               fmaxf(sm.row.red[2], sm.row.red[3]));
        float s = 0.f;
        for (int tt = tid; tt < 384; tt += 256){
          float wvv = (tt < len) ? __expf(sm.row.e[tt] - mx) : 0.f;
          sm.row.w[tt] = wvv; s += wvv;
        }
        for (int o = 32; o; o >>= 1) s += __shfl_xor(s, o, 64);
        if ((tid & 63) == 0) sm.row.red[8 + (tid >> 6)] = s;
        __syncthreads();
        const float inv = 1.f/(sm.row.red[8]+sm.row.red[9]+sm.row.red[10]+sm.row.red[11]);
        for (int tt = tid; tt < 384; tt += 256){
          float wvv = sm.row.w[tt]*inv;
          sm.row.w[tt] = wvv;
          astf(ws + AW_F + b*384 + tt, wvv);
          float oldc = aldf(ws + AWC_F + b*384 + tt);
          astf(ws + AWC_F + b*384 + tt, oldc + wvv);
          P.out[ALIGN0 + ((long long)b*400 + t)*384 + tt] = wvv;
        }
        __syncthreads();
        // ctx: wave-split over t (4 x 96), lane owns 8 contiguous e-columns.
        // Two float4 loads per t = 1KB coalesced per wave-instruction.
        {
          const float* mrow = P.memory + (long long)b*196608;
          float acc[8] = {0,0,0,0,0,0,0,0};
          const int e0 = lane*8;
          const int tlo = wv*96;
          #pragma unroll 4
          for (int tt2 = tlo; tt2 < tlo + 96; ++tt2){
            const float wt = sm.row.w[tt2];
            const float* mp = mrow + (long long)tt2*512 + e0;
            float4 m0 = *reinterpret_cast<const float4*>(mp);
            float4 m1 = *reinterpret_cast<const float4*>(mp+4);
            acc[0] += wt*m0.x; acc[1] += wt*m0.y; acc[2] += wt*m0.z; acc[3] += wt*m0.w;
            acc[4] += wt*m1.x; acc[5] += wt*m1.y; acc[6] += wt*m1.z; acc[7] += wt*m1.w;
          }
          #pragma unroll
          for (int j = 0; j < 8; ++j) sm.row.ctxred[wv][e0+j] = acc[j];
          __syncthreads();
          for (int e = tid; e < 512; e += 256){
            float v = sm.row.ctxred[0][e] + sm.row.ctxred[1][e]
                    + sm.row.ctxred[2][e] + sm.row.ctxred[3][e];
            asth(wsh + CTXF_H + b*512 + e, v);
          }
        }
      }
    } else if (bid < 288){
      // dec-LSTM ah/dh partial (K=2048): 16 rows/block via MFMA.
      // A-tiles prefetched: 16 x 16B in flight per wave.
      if (t < 400){
        const int n0 = (bid-32)*16;
        const int n = n0 + i16;
        f32x4 acc0 = {0,0,0,0}, acc1 = {0,0,0,0};
        const long long curO = (long long)cur*32768;
        half8 Areg[16];
        #pragma unroll
        for (int i = 0; i < 16; ++i){
          const int k0 = (wv*16 + i)*32;
          const h16* pA = (k0 < 1024) ? wsh + DWIHF_H + (long long)n*1536 + k0 + q*8
                                      : wsh + DWHHF_H + (long long)n*1024 + (k0-1024) + q*8;
          Areg[i] = *(const half8*)pA;
        }
        #pragma unroll
        for (int i = 0; i < 16; ++i){
          const int k0 = (wv*16 + i)*32;
          half8 B0, B1;
          if (k0 < 1024){
            B0 = ald16(wsh + AHF_H + curO + i16*1024 + k0 + q*8);
            B1 = ald16(wsh + AHF_H + curO + (16+i16)*1024 + k0 + q*8);
          } else {
            B0 = ald16(wsh + DHF_H + i16*1024 + (k0-1024) + q*8);
            B1 = ald16(wsh + DHF_H + (16+i16)*1024 + (k0-1024) + q*8);
          }
          acc0 = MFMA16(Areg[i], B0, acc0);
          acc1 = MFMA16(Areg[i], B1, acc1);
        }
        #pragma unroll
        for (int r = 0; r < 4; ++r){
          sm.g.red[wv][0][q*4+r][i16] = acc0[r];
          sm.g.red[wv][1][q*4+r][i16] = acc1[r];
        }
        __syncthreads();
        {
          const int r16 = tid & 15, c = tid >> 4;
          #pragma unroll
          for (int bt = 0; bt < 2; ++bt){
            float v = sm.g.red[0][bt][r16][c] + sm.g.red[1][bt][r16][c]
                    + sm.g.red[2][bt][r16][c] + sm.g.red[3][bt][r16][c];
            astf(ws + DPART_F + (long long)(bt*16 + c)*4096 + n0 + r16, v);
          }
        }
      }
    } else if (bid < 320){
      // mel + gate projections for step t-1 (fp32 VALU)
      if (t >= 1){
        const int b = bid - 288;
        for (int i = tid; i < 384; i += 256){
          union { unsigned long long u; h16 h[4]; } hu;
          hu.u = (i < 256) ? aldu64(wsh + DHF_H + b*1024 + i*4)
                           : aldu64(wsh + CTXF_H + b*512 + (i-256)*4);
          #pragma unroll
          for (int j = 0; j < 4; ++j) sm.mel.hc[i*4+j] = (float)hu.h[j];
        }
        __syncthreads();
        if (tid < 160){
          const int r = tid >> 1, h2 = tid & 1;
          const float* pr  = P.pw + (long long)r*1536 + h2*768;
          const float* hcp = &sm.mel.hc[h2*768];
          float acc = 0.f;
          for (int k = 0; k < 768; k += 4){
            float4 wq = *reinterpret_cast<const float4*>(pr + k);
            acc += wq.x*hcp[k] + wq.y*hcp[k+1] + wq.z*hcp[k+2] + wq.w*hcp[k+3];
          }
          sm.mel.mp[r][h2] = acc;
        } else if (tid >= 192){
          const int l = tid - 192;
          const float* gp  = P.gw + l*24;
          const float* hcp = &sm.mel.hc[l*24];
          float acc = 0.f;
          #pragma unroll
          for (int k = 0; k < 24; ++k) acc += gp[k]*hcp[k];
          for (int o = 32; o; o >>= 1) acc += __shfl_xor(acc, o, 64);
          if (l == 0) sm.mel.gacc = acc;
        }
        __syncthreads();
        if (tid < 80)
          P.out[((long long)b*80 + tid)*400 + (t-1)] = sm.mel.mp[tid][0] + sm.mel.mp[tid][1] + P.pb[tid];
        if (tid == 80)
          P.out[GATE0 + (long long)b*400 + (t-1)] = sm.mel.gacc + P.gb[0];
      }
    }
    gbar(bar, ++ep, false);
  }
}

extern "C" void kernel_launch(void* const* d_in, const int* in_sizes, int n_in,
                              void* d_out, int out_size, void* d_ws, size_t ws_size,
                              hipStream_t stream) {
  (void)in_sizes; (void)n_in; (void)out_size; (void)ws_size;
  Params p;
  p.memory = (const float*)d_in[0];
  p.dec_in = (const float*)d_in[1];
  p.memlen = (const int*)d_in[2];
  p.w1   = (const float*)d_in[3];
  p.w2   = (const float*)d_in[4];
  p.awih = (const float*)d_in[5];
  p.awhh = (const float*)d_in[6];
  p.abih = (const float*)d_in[7];
  p.abhh = (const float*)d_in[8];
  p.qw   = (const float*)d_in[9];
  p.mw   = (const float*)d_in[10];
  p.vw   = (const float*)d_in[11];
  p.lcw  = (const float*)d_in[12];
  p.ldw  = (const float*)d_in[13];
  p.dwih = (const float*)d_in[14];
  p.dwhh = (const float*)d_in[15];
  p.dbih = (const float*)d_in[16];
  p.dbhh = (const float*)d_in[17];
  p.pw   = (const float*)d_in[18];
  p.pb   = (const float*)d_in[19];
  p.gw   = (const float*)d_in[20];
  p.gb   = (const float*)d_in[21];
  p.out  = (float*)d_out;
  p.ws   = (float*)d_ws;

  hipLaunchKernelGGL(init_kernel, dim3(1), dim3(512), 0, stream, p.ws);
  hipLaunchKernelGGL(decoder_kernel, dim3(512), dim3(256), 0, stream, p);
}

// Round 4
// 57627.344 us; speedup vs baseline: 1.2233x; 1.2233x over previous
//
#include <hip/hip_runtime.h>

typedef _Float16 h16;
typedef _Float16 half8 __attribute__((ext_vector_type(8)));
typedef float f32x4 __attribute__((ext_vector_type(4)));

#define NEGV -1000000000.0f
#define MFMA16(a,b,c) __builtin_amdgcn_mfma_f32_16x16x32_f16(a,b,c,0,0,0)

struct Params {
  const float *memory, *dec_in; const int *memlen;
  const float *w1, *w2;
  const float *awih, *awhh, *abih, *abhh;
  const float *qw, *mw, *vw, *lcw, *ldw;
  const float *dwih, *dwhh, *dbih, *dbhh;
  const float *pw, *pb, *gw, *gb;
  float *out, *ws;
};

// ---- ws layout ----
// f16 arrays: offsets in HALFS
constexpr long long XALLF_H = 0;          // 400*32*256  xallf[t][b][256]
constexpr long long PMH_H   = 3276800;    // 32*128*384  pm[b][a][t]
constexpr long long PLB_H   = 4849664;    // 32*384*128  plb[b][t][a]
constexpr long long AWIHF_H = 6422528;    // 4096*768
constexpr long long AWHHF_H = 9568256;    // 4096*1024
constexpr long long DWIHF_H = 13762560;   // 4096*1536
constexpr long long DWHHF_H = 20054016;   // 4096*1024
constexpr long long LCWF_H  = 24248320;   // 32*64 (padded conv wts, f-major)
constexpr long long LDWF_H  = 24250368;   // 128*32 (a-major)
constexpr long long AHF_H   = 24254464;   // 2 * 32*1024 (double buffered)
constexpr long long DHF_H   = 24320000;   // 32*1024
constexpr long long CTXF_H  = 24352768;   // 32*512
// f16 read-only copies of per-step-streamed fp32 tensors (bytes halved):
constexpr long long MEMF_H  = 24812544;   // 32*384*512 memory (f16)
constexpr long long PWF_H   = 31104000;   // 80*1536 proj weights (f16)
// fp32 arrays: offsets in FLOATS
constexpr long long ZERO_F0 = 12127232;   // zero region start (covers AHF..DPART)
constexpr long long AC_F    = 12184576;   // 32*1024
constexpr long long DC_F    = 12217344;   // 32*1024
constexpr long long AW_F    = 12250112;   // 32*384
constexpr long long AWC_F   = 12262400;   // 32*384
constexpr long long DPART_F = 12274688;   // 32*4096
constexpr long long BAR_F   = 12405760;   // 512 uints
constexpr int  ZERO_LEN = 278528;
constexpr unsigned NBLK = 512;
// out layout
constexpr long long GATE0  = 1024000;
constexpr long long ALIGN0 = 1036800;

union SMem {
  float pmstage[12][512];                                     // 24.6 KB
  struct { float x[5][80]; float l1[5][256]; } pre;
  struct { float red[4][2][16][17]; } g;                      // 8.7 KB
  struct { float awseg[2][128]; h16 im2[96][72]; h16 locT[96][32];
           unsigned p16[96][64]; } ploc;                      // 45.6 KB (max)
  struct { float ah[1024]; float pq[128]; float pqp[2][128]; float vv[128];
           float e[384]; float w[384]; float red[16]; } row;
  struct { float hc[1536]; float mp[80][2]; float gacc; } mel;
};

__device__ __forceinline__ float sigf(float x){ return 1.0f/(1.0f+__expf(-x)); }
__device__ __forceinline__ float tanhfast(float x){ float e2 = __expf(2.0f*x); return 1.0f - 2.0f/(e2+1.0f); }

// ---- agent-scope (cross-XCD coherent, cache-bypassing) accessors ----
__device__ __forceinline__ float aldf(const float* p){
  return __hip_atomic_load(p, __ATOMIC_RELAXED, __HIP_MEMORY_SCOPE_AGENT);
}
__device__ __forceinline__ void astf(float* p, float v){
  __hip_atomic_store(p, v, __ATOMIC_RELAXED, __HIP_MEMORY_SCOPE_AGENT);
}
__device__ __forceinline__ unsigned long long aldu64(const h16* p){
  return __hip_atomic_load((const unsigned long long*)p, __ATOMIC_RELAXED, __HIP_MEMORY_SCOPE_AGENT);
}
__device__ __forceinline__ half8 ald16(const h16* p){
  union { unsigned long long q[2]; half8 v; } u;
  u.q[0] = __hip_atomic_load((const unsigned long long*)p,     __ATOMIC_RELAXED, __HIP_MEMORY_SCOPE_AGENT);
  u.q[1] = __hip_atomic_load(((const unsigned long long*)p)+1, __ATOMIC_RELAXED, __HIP_MEMORY_SCOPE_AGENT);
  return u.v;
}
__device__ __forceinline__ void asth(h16* p, float v){
  union { h16 h; unsigned short s; } u; u.h = (h16)v;
  __hip_atomic_store((unsigned short*)p, u.s, __ATOMIC_RELAXED, __HIP_MEMORY_SCOPE_AGENT);
}
__device__ __forceinline__ void astu32(unsigned* p, unsigned v){
  __hip_atomic_store(p, v, __ATOMIC_RELAXED, __HIP_MEMORY_SCOPE_AGENT);
}

// software grid barrier; full=true adds release/acquire cache maintenance
__device__ __forceinline__ void gbar(unsigned* cnts, unsigned ep, bool full){
  __syncthreads();
  if (threadIdx.x == 0){
    if (full) __threadfence();
    __hip_atomic_fetch_add(&cnts[(blockIdx.x & 7)*64], 1u, __ATOMIC_RELEASE, __HIP_MEMORY_SCOPE_AGENT);
    const unsigned tgt = ep*NBLK;
    for (;;){
      unsigned s = 0;
      #pragma unroll
      for (int i = 0; i < 8; ++i)
        s += __hip_atomic_load(&cnts[i*64], __ATOMIC_RELAXED, __HIP_MEMORY_SCOPE_AGENT);
      if (s >= tgt) break;
      __builtin_amdgcn_s_sleep(4);
    }
    if (full) __threadfence();
  }
  __syncthreads();
}

__global__ void init_kernel(float* ws){
  unsigned* c = (unsigned*)(ws + BAR_F);
  if (threadIdx.x < 512) c[threadIdx.x] = 0u;
}

__global__ __launch_bounds__(256, 2)
void decoder_kernel(Params P){
  __shared__ SMem sm;
  const int tid = threadIdx.x;
  const int bid = blockIdx.x;
  float* ws = P.ws;
  h16*   wsh = (h16*)ws;
  unsigned* bar = (unsigned*)(ws + BAR_F);
  unsigned ep = 0;

  const int lane = tid & 63, wv = tid >> 6;
  const int i16 = lane & 15, q = lane >> 4;

  // ============== PROLOGUE ==============
  {
    const long long gtid = (long long)bid*256 + tid;
    // zero state region
    for (long long i = gtid; i < ZERO_LEN; i += 131072) ws[ZERO_F0 + i] = 0.f;
    // weight f16 conversion
    for (long long i = gtid; i < 3145728; i += 131072) wsh[AWIHF_H+i] = (h16)P.awih[i];
    for (long long i = gtid; i < 4194304; i += 131072) wsh[AWHHF_H+i] = (h16)P.awhh[i];
    for (long long i = gtid; i < 6291456; i += 131072) wsh[DWIHF_H+i] = (h16)P.dwih[i];
    for (long long i = gtid; i < 4194304; i += 131072) wsh[DWHHF_H+i] = (h16)P.dwhh[i];
    // f16 copies of the two big per-step fp32 read streams (halves bytes):
    for (long long i = gtid; i < 6291456; i += 131072) wsh[MEMF_H+i] = (h16)P.memory[i];
    for (long long i = gtid; i < 122880; i += 131072) wsh[PWF_H+i] = (h16)P.pw[i];
    for (long long i = gtid; i < 2048; i += 131072){
      int f = (int)(i >> 6), kk = (int)(i & 63), ch = kk >> 5, k = kk & 31;
      wsh[LCWF_H+i] = (k < 31) ? (h16)P.lcw[f*62 + ch*31 + k] : (h16)0.f;
    }
    for (long long i = gtid; i < 4096; i += 131072) wsh[LDWF_H+i] = (h16)P.ldw[i];
  }
  // processed_memory -> PMH (f16)
  {
    const int b = bid >> 4, part = bid & 15;
    for (int sub = 0; sub < 2; ++sub){
      const int t0 = part*24 + sub*12;
      __syncthreads();
      for (int i = tid; i < 1536; i += 256){
        int row = i >> 7, c4 = (i & 127) << 2;
        *reinterpret_cast<float4*>(&sm.pmstage[row][c4]) =
          *reinterpret_cast<const float4*>(P.memory + ((long long)(b*384 + t0 + row))*512 + c4);
      }
      __syncthreads();
      const int a = tid & 127, th = tid >> 7;
      float acc[6] = {0,0,0,0,0,0};
      const float* mwr = P.mw + (long long)a*512;
      for (int e = 0; e < 512; ++e){
        float wvv = mwr[e];
        #pragma unroll
        for (int jj = 0; jj < 6; ++jj) acc[jj] += wvv*sm.pmstage[th*6+jj][e];
      }
      #pragma unroll
      for (int jj = 0; jj < 6; ++jj)
        wsh[PMH_H + ((long long)b*128 + a)*384 + t0 + th*6 + jj] = (h16)acc[jj];
    }
  }
  // prenet -> XALLF (f16)
  {
    for (int batch = 0; batch < 5; ++batch){
      const int pbase = bid*25 + batch*5;
      __syncthreads();
      for (int i = tid; i < 400; i += 256){
        int j = i/80, m = i%80;
        int p = pbase + j; int tq = p >> 5, bb = p & 31;
        float v = 0.f;
        if (tq > 0) v = P.dec_in[((long long)bb*80 + m)*400 + (tq-1)];
        sm.pre.x[j][m] = v;
      }
      __syncthreads();
      {
        float acc[5] = {0,0,0,0,0};
        const float* w1r = P.w1 + (long long)tid*80;
        for (int m = 0; m < 80; ++m){
          float wvv = w1r[m];
          #pragma unroll
          for (int j = 0; j < 5; ++j) acc[j] += wvv*sm.pre.x[j][m];
        }
        __syncthreads();
        #pragma unroll
        for (int j = 0; j < 5; ++j) sm.pre.l1[j][tid] = fmaxf(acc[j], 0.f);
      }
      __syncthreads();
      {
        float acc[5] = {0,0,0,0,0};
        const float* w2r = P.w2 + (long long)tid*256;
        for (int pp = 0; pp < 256; ++pp){
          float wvv = w2r[pp];
          #pragma unroll
          for (int j = 0; j < 5; ++j) acc[j] += wvv*sm.pre.l1[j][pp];
        }
        #pragma unroll
        for (int j = 0; j < 5; ++j){
          int p = pbase + j; int tq = p >> 5, bb = p & 31;
          wsh[XALLF_H + ((long long)tq*32 + bb)*256 + tid] = (h16)fmaxf(acc[j], 0.f);
        }
      }
    }
  }
  gbar(bar, ++ep, true);   // full fence once: weights/PMH/XALLF now visible + cached

  // ============== MAIN LOOP ==============
  for (int t = 0; t <= 400; ++t){
    const int cur = t & 1, prv = (t+1) & 1;

    // ---------- PHASE A ----------
    if (bid < 256){
      // att-LSTM: 4 units/block via MFMA, waves split K (56 steps = 4x14)
      if (t < 400){
        const int u0 = bid*4;
        const int n = ((i16 >> 2)*1024) + u0 + (i16 & 3);   // gate-gathered row
        f32x4 acc0 = {0,0,0,0}, acc1 = {0,0,0,0};
        const long long prvO = (long long)prv*32768;
        for (int s = wv*14; s < wv*14 + 14; ++s){
          const int k0 = s*32;
          const h16* pA = (k0 < 768) ? wsh + AWIHF_H + (long long)n*768 + k0 + q*8
                                     : wsh + AWHHF_H + (long long)n*1024 + (k0-768) + q*8;
          half8 A = *(const half8*)pA;
          half8 B0, B1;
          if (k0 < 256){
            B0 = *(const half8*)(wsh + XALLF_H + ((long long)t*32 + i16)*256 + k0 + q*8);
            B1 = *(const half8*)(wsh + XALLF_H + ((long long)t*32 + 16 + i16)*256 + k0 + q*8);
          } else if (k0 < 768){
            B0 = ald16(wsh + CTXF_H + i16*512 + (k0-256) + q*8);
            B1 = ald16(wsh + CTXF_H + (16+i16)*512 + (k0-256) + q*8);
          } else {
            B0 = ald16(wsh + AHF_H + prvO + i16*1024 + (k0-768) + q*8);
            B1 = ald16(wsh + AHF_H + prvO + (16+i16)*1024 + (k0-768) + q*8);
          }
          acc0 = MFMA16(A, B0, acc0);
          acc1 = MFMA16(A, B1, acc1);
        }
        #pragma unroll
        for (int r = 0; r < 4; ++r){
          sm.g.red[wv][0][q*4+r][i16] = acc0[r];
          sm.g.red[wv][1][q*4+r][i16] = acc1[r];
        }
        __syncthreads();
        if (tid < 128){
          const int uu = tid >> 5, b = tid & 31;
          const int bt = b >> 4, c = b & 15;
          float g4[4];
          #pragma unroll
          for (int g = 0; g < 4; ++g){
            const int tr = g*4 + uu;
            float v = sm.g.red[0][bt][tr][c] + sm.g.red[1][bt][tr][c]
                    + sm.g.red[2][bt][tr][c] + sm.g.red[3][bt][tr][c];
            const int ng = g*1024 + u0 + uu;
            g4[g] = v + P.abih[ng] + P.abhh[ng];
          }
          const long long idx = (long long)b*1024 + u0 + uu;
          float c2 = sigf(g4[1])*ws[AC_F + idx] + sigf(g4[0])*tanhfast(g4[2]);
          ws[AC_F + idx] = c2;
          asth(wsh + AHF_H + (long long)cur*32768 + idx, sigf(g4[3])*tanhfast(c2));
        }
      }
    } else if (bid < 384){
      // loc conv + dense via MFMA -> plb f16 [b][t][a]
      if (t < 400){
        const int pb = bid - 256, b = pb >> 2, tbase = (pb & 3)*96;
        for (int i = tid; i < 252; i += 256){
          int ch = i / 126, ix = i % 126;
          int pos = tbase - 15 + ix;
          float v = 0.f;
          if (pos >= 0 && pos < 384)
            v = aldf(ws + (ch ? AWC_F : AW_F) + b*384 + pos);
          sm.ploc.awseg[ch][ix] = v;
        }
        __syncthreads();
        for (int i = tid; i < 96*64; i += 256){
          int tt = i >> 6, kk = i & 63, ch = kk >> 5, k = kk & 31;
          sm.ploc.im2[tt][kk] = (k < 31) ? (h16)sm.ploc.awseg[ch][tt + k] : (h16)0.f;
        }
        __syncthreads();
        // conv: out[t'][f] = sum_k im2[t'][k] * lcwf[f][k]; 12 tiles, 3/wave
        #pragma unroll
        for (int p = 0; p < 3; ++p){
          int tile = wv + p*4;
          int tT = tile % 6, tF = tile / 6;
          f32x4 a = {0,0,0,0};
          #pragma unroll
          for (int ks = 0; ks < 2; ++ks){
            half8 A = *(const half8*)&sm.ploc.im2[tT*16 + i16][ks*32 + q*8];
            half8 B = *(const half8*)(wsh + LCWF_H + (tF*16 + i16)*64 + ks*32 + q*8);
            a = MFMA16(A, B, a);
          }
          #pragma unroll
          for (int r = 0; r < 4; ++r)
            sm.ploc.locT[tT*16 + q*4 + r][tF*16 + i16] = (h16)a[r];
        }
        __syncthreads();
        // dense: plb[t'][a] = pm + sum_f locT[t'][f]*ldw[a][f]; 48 tiles, 12/wave
        unsigned short* s16 = (unsigned short*)&sm.ploc.p16[0][0];
        #pragma unroll
        for (int p = 0; p < 12; ++p){
          int tile = wv + p*4;
          int tT = tile % 6, tA = tile / 6;
          half8 A = *(const half8*)&sm.ploc.locT[tT*16 + i16][q*8];
          half8 B = *(const half8*)(wsh + LDWF_H + (tA*16 + i16)*32 + q*8);
          f32x4 a = {0,0,0,0};
          a = MFMA16(A, B, a);
          int aa = tA*16 + i16;
          union { unsigned long long u; h16 h[4]; } pmu;
          pmu.u = *(const unsigned long long*)
              (wsh + PMH_H + ((long long)b*128 + aa)*384 + tbase + tT*16 + q*4);
          #pragma unroll
          for (int r = 0; r < 4; ++r){
            union { h16 h; unsigned short s; } cv;
            cv.h = (h16)(a[r] + (float)pmu.h[r]);
            s16[(tT*16 + q*4 + r)*128 + aa] = cv.s;
          }
        }
        __syncthreads();
        unsigned* plbu = (unsigned*)(wsh + PLB_H);
        for (int i = tid; i < 96*64; i += 256){
          int tt = i >> 6, a2 = i & 63;
          astu32(plbu + ((long long)b*384 + tbase + tt)*64 + a2, sm.ploc.p16[tt][a2]);
        }
      }
    } else {
      // dec-LSTM ctx-part (K=512) + cell for step t-1: 8 units/block
      if (t >= 1){
        const int u0 = (bid-384)*8;
        const int jt = wv & 1, kh = wv >> 1;
        const int n = ((i16 >> 2)*1024) + u0 + jt*4 + (i16 & 3);
        f32x4 acc0 = {0,0,0,0}, acc1 = {0,0,0,0};
        for (int s = kh*8; s < kh*8 + 8; ++s){
          const int k0 = s*32;
          half8 A = *(const half8*)(wsh + DWIHF_H + (long long)n*1536 + 1024 + k0 + q*8);
          half8 B0 = ald16(wsh + CTXF_H + i16*512 + k0 + q*8);
          half8 B1 = ald16(wsh + CTXF_H + (16+i16)*512 + k0 + q*8);
          acc0 = MFMA16(A, B0, acc0);
          acc1 = MFMA16(A, B1, acc1);
        }
        #pragma unroll
        for (int r = 0; r < 4; ++r){
          sm.g.red[wv][0][q*4+r][i16] = acc0[r];
          sm.g.red[wv][1][q*4+r][i16] = acc1[r];
        }
        __syncthreads();
        {
          const int uu8 = tid >> 5, b = tid & 31;
          const int j2 = uu8 >> 2, uu = uu8 & 3;
          const int bt = b >> 4, c = b & 15;
          const int unit = u0 + j2*4 + uu;
          float g4[4];
          #pragma unroll
          for (int g = 0; g < 4; ++g){
            const int tr = g*4 + uu;
            const int ng = g*1024 + unit;
            g4[g] = sm.g.red[j2][bt][tr][c] + sm.g.red[j2+2][bt][tr][c]
                  + aldf(ws + DPART_F + (long long)b*4096 + ng)
                  + P.dbih[ng] + P.dbhh[ng];
          }
          const long long idx = (long long)b*1024 + unit;
          float c2 = sigf(g4[1])*ws[DC_F + idx] + sigf(g4[0])*tanhfast(g4[2]);
          ws[DC_F + idx] = c2;
          asth(wsh + DHF_H + idx, sigf(g4[3])*tanhfast(c2));
        }
      }
    }
    gbar(bar, ++ep, false);

    // ---------- PHASE B ----------
    if (bid < 32){
      // attention: pq, energies, softmax, ctx, aw/awc, alignments
      if (t < 400){
        const int b = bid;
        const int len = P.memlen[b];
        {
          union { unsigned long long u; h16 h[4]; } hu;
          hu.u = aldu64(wsh + AHF_H + (long long)cur*32768 + b*1024 + tid*4);
          #pragma unroll
          for (int j = 0; j < 4; ++j) sm.row.ah[tid*4+j] = (float)hu.h[j];
        }
        if (tid < 128) sm.row.vv[tid] = P.vw[tid];
        __syncthreads();
        {
          const int a = tid & 127, kh2 = tid >> 7;
          const float* qr  = P.qw + (long long)a*1024 + kh2*512;
          const float* ahs = &sm.row.ah[kh2*512];
          float acc = 0.f;
          for (int k = 0; k < 512; k += 4){
            float4 wq = *reinterpret_cast<const float4*>(qr + k);
            acc += wq.x*ahs[k] + wq.y*ahs[k+1] + wq.z*ahs[k+2] + wq.w*ahs[k+3];
          }
          sm.row.pqp[kh2][a] = acc;
        }
        __syncthreads();
        if (tid < 128) sm.row.pq[tid] = sm.row.pqp[0][tid] + sm.row.pqp[1][tid];
        __syncthreads();
        for (int pass = 0; pass < 2; ++pass){
          const int tt = tid + pass*256;
          if (tt < 384){
            float acc;
            if (tt < len){
              acc = 0.f;
              const unsigned long long* plp = (const unsigned long long*)
                  (wsh + PLB_H + ((long long)b*384 + tt)*128);
              for (int a0 = 0; a0 < 32; ++a0){
                union { unsigned long long u; h16 h[4]; } hu;
                hu.u = __hip_atomic_load(plp + a0, __ATOMIC_RELAXED, __HIP_MEMORY_SCOPE_AGENT);
                #pragma unroll
                for (int j = 0; j < 4; ++j)
                  acc += sm.row.vv[a0*4+j]*tanhfast(sm.row.pq[a0*4+j] + (float)hu.h[j]);
              }
            } else acc = NEGV;
            sm.row.e[tt] = acc;
          }
        }
        __syncthreads();
        float m = NEGV;
        for (int tt = tid; tt < 384; tt += 256) m = fmaxf(m, sm.row.e[tt]);
        for (int o = 32; o; o >>= 1) m = fmaxf(m, __shfl_xor(m, o, 64));
        if ((tid & 63) == 0) sm.row.red[tid >> 6] = m;
        __syncthreads();
        const float mx = fmaxf(fmaxf(sm.row.red[0], sm.row.red[1]),
                               fmaxf(sm.row.red[2], sm.row.red[3]));
        float s = 0.f;
        for (int tt = tid; tt < 384; tt += 256){
          float wvv = (tt < len) ? __expf(sm.row.e[tt] - mx) : 0.f;
          sm.row.w[tt] = wvv; s += wvv;
        }
        for (int o = 32; o; o >>= 1) s += __shfl_xor(s, o, 64);
        if ((tid & 63) == 0) sm.row.red[8 + (tid >> 6)] = s;
        __syncthreads();
        const float inv = 1.f/(sm.row.red[8]+sm.row.red[9]+sm.row.red[10]+sm.row.red[11]);
        for (int tt = tid; tt < 384; tt += 256){
          float wvv = sm.row.w[tt]*inv;
          sm.row.w[tt] = wvv;
          astf(ws + AW_F + b*384 + tt, wvv);
          float oldc = aldf(ws + AWC_F + b*384 + tt);
          astf(ws + AWC_F + b*384 + tt, oldc + wvv);
          P.out[ALIGN0 + ((long long)b*400 + t)*384 + tt] = wvv;
        }
        __syncthreads();
        // ctx from f16 memory copy: per row one u32 (2 elems) per lane ->
        // half the bytes and half the load instructions of the fp32 version.
        {
          const unsigned* mrow = (const unsigned*)(wsh + MEMF_H) + (long long)b*98304;
          float acc0 = 0.f, acc1 = 0.f;
          for (int t4 = 0; t4 < 96; ++t4){
            float4 w4 = *reinterpret_cast<const float4*>(&sm.row.w[t4*4]);
            const unsigned* m0 = mrow + t4*1024 + tid;
            unsigned v0 = m0[0], v1 = m0[256], v2 = m0[512], v3 = m0[768];
            union { unsigned u; h16 h[2]; } d0, d1, d2, d3;
            d0.u = v0; d1.u = v1; d2.u = v2; d3.u = v3;
            acc0 += w4.x*(float)d0.h[0] + w4.y*(float)d1.h[0]
                  + w4.z*(float)d2.h[0] + w4.w*(float)d3.h[0];
            acc1 += w4.x*(float)d0.h[1] + w4.y*(float)d1.h[1]
                  + w4.z*(float)d2.h[1] + w4.w*(float)d3.h[1];
          }
          union { h16 h[2]; unsigned u; } cv;
          cv.h[0] = (h16)acc0; cv.h[1] = (h16)acc1;
          astu32((unsigned*)(wsh + CTXF_H) + b*256 + tid, cv.u);
        }
      }
    } else if (bid < 288){
      // dec-LSTM ah/dh partial (K=2048): 16 rows/block via MFMA
      if (t < 400){
        const int n0 = (bid-32)*16;
        const int n = n0 + i16;
        f32x4 acc0 = {0,0,0,0}, acc1 = {0,0,0,0};
        const long long curO = (long long)cur*32768;
        for (int s = wv*16; s < wv*16 + 16; ++s){
          const int k0 = s*32;
          const h16* pA = (k0 < 1024) ? wsh + DWIHF_H + (long long)n*1536 + k0 + q*8
                                      : wsh + DWHHF_H + (long long)n*1024 + (k0-1024) + q*8;
          half8 A = *(const half8*)pA;
          half8 B0, B1;
          if (k0 < 1024){
            B0 = ald16(wsh + AHF_H + curO + i16*1024 + k0 + q*8);
            B1 = ald16(wsh + AHF_H + curO + (16+i16)*1024 + k0 + q*8);
          } else {
            B0 = ald16(wsh + DHF_H + i16*1024 + (k0-1024) + q*8);
            B1 = ald16(wsh + DHF_H + (16+i16)*1024 + (k0-1024) + q*8);
          }
          acc0 = MFMA16(A, B0, acc0);
          acc1 = MFMA16(A, B1, acc1);
        }
        #pragma unroll
        for (int r = 0; r < 4; ++r){
          sm.g.red[wv][0][q*4+r][i16] = acc0[r];
          sm.g.red[wv][1][q*4+r][i16] = acc1[r];
        }
        __syncthreads();
        {
          const int r16 = tid & 15, c = tid >> 4;
          #pragma unroll
          for (int bt = 0; bt < 2; ++bt){
            float v = sm.g.red[0][bt][r16][c] + sm.g.red[1][bt][r16][c]
                    + sm.g.red[2][bt][r16][c] + sm.g.red[3][bt][r16][c];
            astf(ws + DPART_F + (long long)(bt*16 + c)*4096 + n0 + r16, v);
          }
        }
      }
    } else if (bid < 320){
      // mel + gate projections for step t-1; proj weights from f16 copy
      if (t >= 1){
        const int b = bid - 288;
        for (int i = tid; i < 384; i += 256){
          union { unsigned long long u; h16 h[4]; } hu;
          hu.u = (i < 256) ? aldu64(wsh + DHF_H + b*1024 + i*4)
                           : aldu64(wsh + CTXF_H + b*512 + (i-256)*4);
          #pragma unroll
          for (int j = 0; j < 4; ++j) sm.mel.hc[i*4+j] = (float)hu.h[j];
        }
        __syncthreads();
        if (tid < 160){
          const int r = tid >> 1, h2 = tid & 1;
          const h16* pr = wsh + PWF_H + (long long)r*1536 + h2*768;
          const float* hcp = &sm.mel.hc[h2*768];
          float acc = 0.f;
          for (int k = 0; k < 768; k += 8){
            half8 wq = *(const half8*)(pr + k);
            acc += (float)wq[0]*hcp[k]   + (float)wq[1]*hcp[k+1]
                 + (float)wq[2]*hcp[k+2] + (float)wq[3]*hcp[k+3]
                 + (float)wq[4]*hcp[k+4] + (float)wq[5]*hcp[k+5]
                 + (float)wq[6]*hcp[k+6] + (float)wq[7]*hcp[k+7];
          }
          sm.mel.mp[r][h2] = acc;
        } else if (tid >= 192){
          const int l = tid - 192;
          const float* gp  = P.gw + l*24;
          const float* hcp = &sm.mel.hc[l*24];
          float acc = 0.f;
          #pragma unroll
          for (int k = 0; k < 24; ++k) acc += gp[k]*hcp[k];
          for (int o = 32; o; o >>= 1) acc += __shfl_xor(acc, o, 64);
          if (l == 0) sm.mel.gacc = acc;
        }
        __syncthreads();
        if (tid < 80)
          P.out[((long long)b*80 + tid)*400 + (t-1)] = sm.mel.mp[tid][0] + sm.mel.mp[tid][1] + P.pb[tid];
        if (tid == 80)
          P.out[GATE0 + (long long)b*400 + (t-1)] = sm.mel.gacc + P.gb[0];
      }
    }
    gbar(bar, ++ep, false);
  }
}

extern "C" void kernel_launch(void* const* d_in, const int* in_sizes, int n_in,
                              void* d_out, int out_size, void* d_ws, size_t ws_size,
                              hipStream_t stream) {
  (void)in_sizes; (void)n_in; (void)out_size; (void)ws_size;
  Params p;
  p.memory = (const float*)d_in[0];
  p.dec_in = (const float*)d_in[1];
  p.memlen = (const int*)d_in[2];
  p.w1   = (const float*)d_in[3];
  p.w2   = (const float*)d_in[4];
  p.awih = (const float*)d_in[5];
  p.awhh = (const float*)d_in[6];
  p.abih = (const float*)d_in[7];
  p.abhh = (const float*)d_in[8];
  p.qw   = (const float*)d_in[9];
  p.mw   = (const float*)d_in[10];
  p.vw   = (const float*)d_in[11];
  p.lcw  = (const float*)d_in[12];
  p.ldw  = (const float*)d_in[13];
  p.dwih = (const float*)d_in[14];
  p.dwhh = (const float*)d_in[15];
  p.dbih = (const float*)d_in[16];
  p.dbhh = (const float*)d_in[17];
  p.pw   = (const float*)d_in[18];
  p.pb   = (const float*)d_in[19];
  p.gw   = (const float*)d_in[20];
  p.gb   = (const float*)d_in[21];
  p.out  = (float*)d_out;
  p.ws   = (float*)d_ws;

  hipLaunchKernelGGL(init_kernel, dim3(1), dim3(512), 0, stream, p.ws);
  hipLaunchKernelGGL(decoder_kernel, dim3(512), dim3(256), 0, stream, p);
}

// Round 6
// 43810.248 us; speedup vs baseline: 1.6091x; 1.3154x over previous
//
#include <hip/hip_runtime.h>

typedef _Float16 h16;
typedef _Float16 half8 __attribute__((ext_vector_type(8)));
typedef float f32x4 __attribute__((ext_vector_type(4)));

#define NEGV -1000000000.0f
#define MFMA16(a,b,c) __builtin_amdgcn_mfma_f32_16x16x32_f16(a,b,c,0,0,0)

struct Params {
  const float *memory, *dec_in; const int *memlen;
  const float *w1, *w2;
  const float *awih, *awhh, *abih, *abhh;
  const float *qw, *mw, *vw, *lcw, *ldw;
  const float *dwih, *dwhh, *dbih, *dbhh;
  const float *pw, *pb, *gw, *gb;
  float *out, *ws;
};

// ---- ws layout ----
// f16 arrays: offsets in HALFS
constexpr long long XALLF_H = 0;          // 400*32*256  xallf[t][b][256]
constexpr long long PMH_H   = 3276800;    // 32*128*384  pm[b][a][t]
constexpr long long PLB_H   = 4849664;    // 32*384*128  plb[b][t][a]
constexpr long long AWIHF_H = 6422528;    // 4096*768
constexpr long long AWHHF_H = 9568256;    // 4096*1024
constexpr long long DWIHF_H = 13762560;   // 4096*1536
constexpr long long DWHHF_H = 20054016;   // 4096*1024
constexpr long long LCWF_H  = 24248320;   // 32*64 (padded conv wts, f-major)
constexpr long long LDWF_H  = 24250368;   // 128*32 (a-major)
constexpr long long AHF_H   = 24254464;   // 2 * 32*1024 (double buffered)
constexpr long long DHF_H   = 24320000;   // 32*1024
constexpr long long CTXF_H  = 24352768;   // 32*512
// f16 read-only copies of per-step-streamed fp32 tensors (bytes halved):
constexpr long long MEMF_H  = 24812544;   // 32*384*512 memory (f16)
constexpr long long PWF_H   = 31104000;   // 80*1536 proj weights (f16)
// fp32 arrays: offsets in FLOATS
constexpr long long ZERO_F0 = 12127232;   // zero region start (covers AHF..DPART)
constexpr long long AC_F    = 12184576;   // 32*1024
constexpr long long DC_F    = 12217344;   // 32*1024
constexpr long long AW_F    = 12250112;   // 32*384
constexpr long long AWC_F   = 12262400;   // 32*384
constexpr long long DPART_F = 12274688;   // 32*4096
constexpr long long BAR_F   = 12405760;   // 512 uints
constexpr int  ZERO_LEN = 278528;
constexpr unsigned NBLK = 512;
// out layout
constexpr long long GATE0  = 1024000;
constexpr long long ALIGN0 = 1036800;

union SMem {
  float pmstage[12][512];                                     // 24.6 KB
  struct { float x[5][80]; float l1[5][256]; } pre;
  struct { float red[8][2][16][17]; } g;                      // 17.4 KB (8 waves)
  struct { float awseg[2][128]; h16 im2[96][72]; h16 locT[96][32];
           unsigned p16[96][64]; } ploc;                      // 45.6 KB (max)
  struct { float ah[1024]; float pq[128]; float pqp[4][128]; float vv[128];
           float e[384]; float w[384]; float red[16];
           float ctxred[2][256][2]; } row;                    // 14.4 KB
  struct { float hc[1536]; float mp[80][4]; float gacc; } mel;
};

__device__ __forceinline__ float sigf(float x){ return 1.0f/(1.0f+__expf(-x)); }
__device__ __forceinline__ float tanhfast(float x){ float e2 = __expf(2.0f*x); return 1.0f - 2.0f/(e2+1.0f); }

// ---- agent-scope (cross-XCD coherent, cache-bypassing) accessors ----
__device__ __forceinline__ float aldf(const float* p){
  return __hip_atomic_load(p, __ATOMIC_RELAXED, __HIP_MEMORY_SCOPE_AGENT);
}
__device__ __forceinline__ void astf(float* p, float v){
  __hip_atomic_store(p, v, __ATOMIC_RELAXED, __HIP_MEMORY_SCOPE_AGENT);
}
__device__ __forceinline__ unsigned long long aldu64(const h16* p){
  return __hip_atomic_load((const unsigned long long*)p, __ATOMIC_RELAXED, __HIP_MEMORY_SCOPE_AGENT);
}
__device__ __forceinline__ half8 ald16(const h16* p){
  union { unsigned long long q[2]; half8 v; } u;
  u.q[0] = __hip_atomic_load((const unsigned long long*)p,     __ATOMIC_RELAXED, __HIP_MEMORY_SCOPE_AGENT);
  u.q[1] = __hip_atomic_load(((const unsigned long long*)p)+1, __ATOMIC_RELAXED, __HIP_MEMORY_SCOPE_AGENT);
  return u.v;
}
__device__ __forceinline__ void asth(h16* p, float v){
  union { h16 h; unsigned short s; } u; u.h = (h16)v;
  __hip_atomic_store((unsigned short*)p, u.s, __ATOMIC_RELAXED, __HIP_MEMORY_SCOPE_AGENT);
}
__device__ __forceinline__ void astu32(unsigned* p, unsigned v){
  __hip_atomic_store(p, v, __ATOMIC_RELAXED, __HIP_MEMORY_SCOPE_AGENT);
}

// software grid barrier; full=true adds release/acquire cache maintenance
__device__ __forceinline__ void gbar(unsigned* cnts, unsigned ep, bool full){
  __syncthreads();
  if (threadIdx.x == 0){
    if (full) __threadfence();
    __hip_atomic_fetch_add(&cnts[(blockIdx.x & 7)*64], 1u, __ATOMIC_RELEASE, __HIP_MEMORY_SCOPE_AGENT);
    const unsigned tgt = ep*NBLK;
    for (;;){
      unsigned s = 0;
      #pragma unroll
      for (int i = 0; i < 8; ++i)
        s += __hip_atomic_load(&cnts[i*64], __ATOMIC_RELAXED, __HIP_MEMORY_SCOPE_AGENT);
      if (s >= tgt) break;
      __builtin_amdgcn_s_sleep(4);
    }
    if (full) __threadfence();
  }
  __syncthreads();
}

__global__ void init_kernel(float* ws){
  unsigned* c = (unsigned*)(ws + BAR_F);
  if (threadIdx.x < 512) c[threadIdx.x] = 0u;
}

// 512 threads/block (8 waves): doubles waves/CU 8->16 at 2 blocks/CU.
// Latency-bound regime => time scales ~1/waves. VGPR capped at 128 by
// __launch_bounds__(512,4): 4 waves/SIMD * 128 = full file, 16 waves/CU.
// Residency check: LDS 45.6KB*2 = 91KB < 160KB; 16 waves/CU <= 32. Exact fit.
__global__ __launch_bounds__(512, 4)
void decoder_kernel(Params P){
  __shared__ SMem sm;
  const int tid = threadIdx.x;
  const int bid = blockIdx.x;
  float* ws = P.ws;
  h16*   wsh = (h16*)ws;
  unsigned* bar = (unsigned*)(ws + BAR_F);
  unsigned ep = 0;

  const int lane = tid & 63, wv = tid >> 6;          // wv in 0..7
  const int i16 = lane & 15, q = lane >> 4;

  // ============== PROLOGUE ==============
  {
    const long long gtid = (long long)bid*512 + tid;
    const long long GS = 262144;
    // zero state region
    for (long long i = gtid; i < ZERO_LEN; i += GS) ws[ZERO_F0 + i] = 0.f;
    // weight f16 conversion
    for (long long i = gtid; i < 3145728; i += GS) wsh[AWIHF_H+i] = (h16)P.awih[i];
    for (long long i = gtid; i < 4194304; i += GS) wsh[AWHHF_H+i] = (h16)P.awhh[i];
    for (long long i = gtid; i < 6291456; i += GS) wsh[DWIHF_H+i] = (h16)P.dwih[i];
    for (long long i = gtid; i < 4194304; i += GS) wsh[DWHHF_H+i] = (h16)P.dwhh[i];
    // f16 copies of the two big per-step fp32 read streams (bytes halved):
    for (long long i = gtid; i < 6291456; i += GS) wsh[MEMF_H+i] = (h16)P.memory[i];
    for (long long i = gtid; i < 122880; i += GS) wsh[PWF_H+i] = (h16)P.pw[i];
    for (long long i = gtid; i < 2048; i += GS){
      int f = (int)(i >> 6), kk = (int)(i & 63), ch = kk >> 5, k = kk & 31;
      wsh[LCWF_H+i] = (k < 31) ? (h16)P.lcw[f*62 + ch*31 + k] : (h16)0.f;
    }
    for (long long i = gtid; i < 4096; i += GS) wsh[LDWF_H+i] = (h16)P.ldw[i];
  }
  // processed_memory -> PMH (f16): 512 threads = 4 row-groups x 128 cols
  {
    const int b = bid >> 4, part = bid & 15;
    for (int sub = 0; sub < 2; ++sub){
      const int t0 = part*24 + sub*12;
      __syncthreads();
      for (int i = tid; i < 1536; i += 512){
        int row = i >> 7, c4 = (i & 127) << 2;
        *reinterpret_cast<float4*>(&sm.pmstage[row][c4]) =
          *reinterpret_cast<const float4*>(P.memory + ((long long)(b*384 + t0 + row))*512 + c4);
      }
      __syncthreads();
      const int a = tid & 127, th = tid >> 7;       // th in 0..3, 3 rows each
      float acc[3] = {0,0,0};
      const float* mwr = P.mw + (long long)a*512;
      for (int e = 0; e < 512; ++e){
        float wvv = mwr[e];
        #pragma unroll
        for (int jj = 0; jj < 3; ++jj) acc[jj] += wvv*sm.pmstage[th*3+jj][e];
      }
      #pragma unroll
      for (int jj = 0; jj < 3; ++jj)
        wsh[PMH_H + ((long long)b*128 + a)*384 + t0 + th*3 + jj] = (h16)acc[jj];
    }
  }
  // prenet -> XALLF (f16): rows 0..255 on threads 0..255
  {
    for (int batch = 0; batch < 5; ++batch){
      const int pbase = bid*25 + batch*5;
      __syncthreads();
      for (int i = tid; i < 400; i += 512){
        int j = i/80, m = i%80;
        int p = pbase + j; int tq = p >> 5, bb = p & 31;
        float v = 0.f;
        if (tq > 0) v = P.dec_in[((long long)bb*80 + m)*400 + (tq-1)];
        sm.pre.x[j][m] = v;
      }
      __syncthreads();
      {
        float acc[5] = {0,0,0,0,0};
        if (tid < 256){
          const float* w1r = P.w1 + (long long)tid*80;
          for (int m = 0; m < 80; ++m){
            float wvv = w1r[m];
            #pragma unroll
            for (int j = 0; j < 5; ++j) acc[j] += wvv*sm.pre.x[j][m];
          }
        }
        __syncthreads();
        if (tid < 256){
          #pragma unroll
          for (int j = 0; j < 5; ++j) sm.pre.l1[j][tid] = fmaxf(acc[j], 0.f);
        }
      }
      __syncthreads();
      if (tid < 256){
        float acc[5] = {0,0,0,0,0};
        const float* w2r = P.w2 + (long long)tid*256;
        for (int pp = 0; pp < 256; ++pp){
          float wvv = w2r[pp];
          #pragma unroll
          for (int j = 0; j < 5; ++j) acc[j] += wvv*sm.pre.l1[j][pp];
        }
        #pragma unroll
        for (int j = 0; j < 5; ++j){
          int p = pbase + j; int tq = p >> 5, bb = p & 31;
          wsh[XALLF_H + ((long long)tq*32 + bb)*256 + tid] = (h16)fmaxf(acc[j], 0.f);
        }
      }
    }
  }
  gbar(bar, ++ep, true);   // full fence once: weights/PMH/XALLF now visible + cached

  // ============== MAIN LOOP ==============
  for (int t = 0; t <= 400; ++t){
    const int cur = t & 1, prv = (t+1) & 1;

    // ---------- PHASE A ----------
    if (bid < 256){
      // att-LSTM: 4 units/block via MFMA, 8 waves split K (56 steps = 8x7)
      if (t < 400){
        const int u0 = bid*4;
        const int n = ((i16 >> 2)*1024) + u0 + (i16 & 3);   // gate-gathered row
        f32x4 acc0 = {0,0,0,0}, acc1 = {0,0,0,0};
        const long long prvO = (long long)prv*32768;
        for (int s = wv*7; s < wv*7 + 7; ++s){
          const int k0 = s*32;
          const h16* pA = (k0 < 768) ? wsh + AWIHF_H + (long long)n*768 + k0 + q*8
                                     : wsh + AWHHF_H + (long long)n*1024 + (k0-768) + q*8;
          half8 A = *(const half8*)pA;
          half8 B0, B1;
          if (k0 < 256){
            B0 = *(const half8*)(wsh + XALLF_H + ((long long)t*32 + i16)*256 + k0 + q*8);
            B1 = *(const half8*)(wsh + XALLF_H + ((long long)t*32 + 16 + i16)*256 + k0 + q*8);
          } else if (k0 < 768){
            B0 = ald16(wsh + CTXF_H + i16*512 + (k0-256) + q*8);
            B1 = ald16(wsh + CTXF_H + (16+i16)*512 + (k0-256) + q*8);
          } else {
            B0 = ald16(wsh + AHF_H + prvO + i16*1024 + (k0-768) + q*8);
            B1 = ald16(wsh + AHF_H + prvO + (16+i16)*1024 + (k0-768) + q*8);
          }
          acc0 = MFMA16(A, B0, acc0);
          acc1 = MFMA16(A, B1, acc1);
        }
        #pragma unroll
        for (int r = 0; r < 4; ++r){
          sm.g.red[wv][0][q*4+r][i16] = acc0[r];
          sm.g.red[wv][1][q*4+r][i16] = acc1[r];
        }
        __syncthreads();
        if (tid < 128){
          const int uu = tid >> 5, b = tid & 31;
          const int bt = b >> 4, c = b & 15;
          float g4[4];
          #pragma unroll
          for (int g = 0; g < 4; ++g){
            const int tr = g*4 + uu;
            float v = 0.f;
            #pragma unroll
            for (int w8 = 0; w8 < 8; ++w8) v += sm.g.red[w8][bt][tr][c];
            const int ng = g*1024 + u0 + uu;
            g4[g] = v + P.abih[ng] + P.abhh[ng];
          }
          const long long idx = (long long)b*1024 + u0 + uu;
          float c2 = sigf(g4[1])*ws[AC_F + idx] + sigf(g4[0])*tanhfast(g4[2]);
          ws[AC_F + idx] = c2;
          asth(wsh + AHF_H + (long long)cur*32768 + idx, sigf(g4[3])*tanhfast(c2));
        }
      }
    } else if (bid < 384){
      // loc conv + dense via MFMA -> plb f16 [b][t][a]
      if (t < 400){
        const int pb = bid - 256, b = pb >> 2, tbase = (pb & 3)*96;
        for (int i = tid; i < 252; i += 512){
          int ch = i / 126, ix = i % 126;
          int pos = tbase - 15 + ix;
          float v = 0.f;
          if (pos >= 0 && pos < 384)
            v = aldf(ws + (ch ? AWC_F : AW_F) + b*384 + pos);
          sm.ploc.awseg[ch][ix] = v;
        }
        __syncthreads();
        for (int i = tid; i < 96*64; i += 512){
          int tt = i >> 6, kk = i & 63, ch = kk >> 5, k = kk & 31;
          sm.ploc.im2[tt][kk] = (k < 31) ? (h16)sm.ploc.awseg[ch][tt + k] : (h16)0.f;
        }
        __syncthreads();
        // conv: 12 tiles over 8 waves
        #pragma unroll
        for (int p = 0; p < 2; ++p){
          int tile = wv + p*8;
          if (tile < 12){
            int tT = tile % 6, tF = tile / 6;
            f32x4 a = {0,0,0,0};
            #pragma unroll
            for (int ks = 0; ks < 2; ++ks){
              half8 A = *(const half8*)&sm.ploc.im2[tT*16 + i16][ks*32 + q*8];
              half8 B = *(const half8*)(wsh + LCWF_H + (tF*16 + i16)*64 + ks*32 + q*8);
              a = MFMA16(A, B, a);
            }
            #pragma unroll
            for (int r = 0; r < 4; ++r)
              sm.ploc.locT[tT*16 + q*4 + r][tF*16 + i16] = (h16)a[r];
          }
        }
        __syncthreads();
        // dense: 48 tiles over 8 waves = 6/wave
        unsigned short* s16 = (unsigned short*)&sm.ploc.p16[0][0];
        #pragma unroll
        for (int p = 0; p < 6; ++p){
          int tile = wv + p*8;
          int tT = tile % 6, tA = tile / 6;
          half8 A = *(const half8*)&sm.ploc.locT[tT*16 + i16][q*8];
          half8 B = *(const half8*)(wsh + LDWF_H + (tA*16 + i16)*32 + q*8);
          f32x4 a = {0,0,0,0};
          a = MFMA16(A, B, a);
          int aa = tA*16 + i16;
          union { unsigned long long u; h16 h[4]; } pmu;
          pmu.u = *(const unsigned long long*)
              (wsh + PMH_H + ((long long)b*128 + aa)*384 + tbase + tT*16 + q*4);
          #pragma unroll
          for (int r = 0; r < 4; ++r){
            union { h16 h; unsigned short s; } cv;
            cv.h = (h16)(a[r] + (float)pmu.h[r]);
            s16[(tT*16 + q*4 + r)*128 + aa] = cv.s;
          }
        }
        __syncthreads();
        unsigned* plbu = (unsigned*)(wsh + PLB_H);
        for (int i = tid; i < 96*64; i += 512){
          int tt = i >> 6, a2 = i & 63;
          astu32(plbu + ((long long)b*384 + tbase + tt)*64 + a2, sm.ploc.p16[tt][a2]);
        }
      }
    } else {
      // dec-LSTM ctx-part (K=512) + cell for step t-1: 8 units/block,
      // 8 waves = 2 unit-quads x 4 K-quarters
      if (t >= 1){
        const int u0 = (bid-384)*8;
        const int jt = wv & 1, kh = wv >> 1;          // kh in 0..3
        const int n = ((i16 >> 2)*1024) + u0 + jt*4 + (i16 & 3);
        f32x4 acc0 = {0,0,0,0}, acc1 = {0,0,0,0};
        for (int s = kh*4; s < kh*4 + 4; ++s){
          const int k0 = s*32;
          half8 A = *(const half8*)(wsh + DWIHF_H + (long long)n*1536 + 1024 + k0 + q*8);
          half8 B0 = ald16(wsh + CTXF_H + i16*512 + k0 + q*8);
          half8 B1 = ald16(wsh + CTXF_H + (16+i16)*512 + k0 + q*8);
          acc0 = MFMA16(A, B0, acc0);
          acc1 = MFMA16(A, B1, acc1);
        }
        #pragma unroll
        for (int r = 0; r < 4; ++r){
          sm.g.red[wv][0][q*4+r][i16] = acc0[r];
          sm.g.red[wv][1][q*4+r][i16] = acc1[r];
        }
        __syncthreads();
        if (tid < 256){
          const int uu8 = tid >> 5, b = tid & 31;
          const int j2 = uu8 >> 2, uu = uu8 & 3;
          const int bt = b >> 4, c = b & 15;
          const int unit = u0 + j2*4 + uu;
          float g4[4];
          #pragma unroll
          for (int g = 0; g < 4; ++g){
            const int tr = g*4 + uu;
            const int ng = g*1024 + unit;
            float v = sm.g.red[j2][bt][tr][c]   + sm.g.red[j2+2][bt][tr][c]
                    + sm.g.red[j2+4][bt][tr][c] + sm.g.red[j2+6][bt][tr][c];
            g4[g] = v + aldf(ws + DPART_F + (long long)b*4096 + ng)
                  + P.dbih[ng] + P.dbhh[ng];
          }
          const long long idx = (long long)b*1024 + unit;
          float c2 = sigf(g4[1])*ws[DC_F + idx] + sigf(g4[0])*tanhfast(g4[2]);
          ws[DC_F + idx] = c2;
          asth(wsh + DHF_H + idx, sigf(g4[3])*tanhfast(c2));
        }
      }
    }
    gbar(bar, ++ep, false);

    // ---------- PHASE B ----------
    if (bid < 32){
      // attention: pq, energies, softmax, ctx, aw/awc, alignments
      if (t < 400){
        const int b = bid;
        const int len = P.memlen[b];
        if (tid < 256){
          union { unsigned long long u; h16 h[4]; } hu;
          hu.u = aldu64(wsh + AHF_H + (long long)cur*32768 + b*1024 + tid*4);
          #pragma unroll
          for (int j = 0; j < 4; ++j) sm.row.ah[tid*4+j] = (float)hu.h[j];
        }
        if (tid < 128) sm.row.vv[tid] = P.vw[tid];
        __syncthreads();
        {
          // pq: 512 threads = 4 K-quarters x 128 rows
          const int a = tid & 127, kh4 = tid >> 7;
          const float* qr  = P.qw + (long long)a*1024 + kh4*256;
          const float* ahs = &sm.row.ah[kh4*256];
          float acc = 0.f;
          for (int k = 0; k < 256; k += 4){
            float4 wq = *reinterpret_cast<const float4*>(qr + k);
            acc += wq.x*ahs[k] + wq.y*ahs[k+1] + wq.z*ahs[k+2] + wq.w*ahs[k+3];
          }
          sm.row.pqp[kh4][a] = acc;
        }
        __syncthreads();
        if (tid < 128) sm.row.pq[tid] = sm.row.pqp[0][tid] + sm.row.pqp[1][tid]
                                      + sm.row.pqp[2][tid] + sm.row.pqp[3][tid];
        __syncthreads();
        // energies: one thread per t (single pass with 512 threads)
        {
          const int tt = tid;
          if (tt < 384){
            float acc;
            if (tt < len){
              acc = 0.f;
              const unsigned long long* plp = (const unsigned long long*)
                  (wsh + PLB_H + ((long long)b*384 + tt)*128);
              for (int a0 = 0; a0 < 32; ++a0){
                union { unsigned long long u; h16 h[4]; } hu;
                hu.u = __hip_atomic_load(plp + a0, __ATOMIC_RELAXED, __HIP_MEMORY_SCOPE_AGENT);
                #pragma unroll
                for (int j = 0; j < 4; ++j)
                  acc += sm.row.vv[a0*4+j]*tanhfast(sm.row.pq[a0*4+j] + (float)hu.h[j]);
              }
            } else acc = NEGV;
            sm.row.e[tt] = acc;
          }
        }
        __syncthreads();
        float m = NEGV;
        for (int tt = tid; tt < 384; tt += 512) m = fmaxf(m, sm.row.e[tt]);
        for (int o = 32; o; o >>= 1) m = fmaxf(m, __shfl_xor(m, o, 64));
        if ((tid & 63) == 0) sm.row.red[tid >> 6] = m;
        __syncthreads();
        float mx = sm.row.red[0];
        #pragma unroll
        for (int w8 = 1; w8 < 8; ++w8) mx = fmaxf(mx, sm.row.red[w8]);
        float s = 0.f;
        for (int tt = tid; tt < 384; tt += 512){
          float wvv = (tt < len) ? __expf(sm.row.e[tt] - mx) : 0.f;
          sm.row.w[tt] = wvv; s += wvv;
        }
        for (int o = 32; o; o >>= 1) s += __shfl_xor(s, o, 64);
        if ((tid & 63) == 0) sm.row.red[8 + (tid >> 6)] = s;
        __syncthreads();
        float ssum = sm.row.red[8];
        #pragma unroll
        for (int w8 = 1; w8 < 8; ++w8) ssum += sm.row.red[8+w8];
        const float inv = 1.f/ssum;
        for (int tt = tid; tt < 384; tt += 512){
          float wvv = sm.row.w[tt]*inv;
          sm.row.w[tt] = wvv;
          astf(ws + AW_F + b*384 + tt, wvv);
          float oldc = aldf(ws + AWC_F + b*384 + tt);
          astf(ws + AWC_F + b*384 + tt, oldc + wvv);
          P.out[ALIGN0 + ((long long)b*400 + t)*384 + tt] = wvv;
        }
        __syncthreads();
        // ctx from f16 memory copy: 512 threads = 2 row-groups x 256 cols
        {
          const int col = tid & 255, rg = tid >> 8;
          const unsigned* mrow = (const unsigned*)(wsh + MEMF_H) + (long long)b*98304;
          float acc0 = 0.f, acc1 = 0.f;
          for (int t4 = rg*48; t4 < rg*48 + 48; ++t4){
            float4 w4 = *reinterpret_cast<const float4*>(&sm.row.w[t4*4]);
            const unsigned* m0 = mrow + t4*1024 + col;
            unsigned v0 = m0[0], v1 = m0[256], v2 = m0[512], v3 = m0[768];
            union { unsigned u; h16 h[2]; } d0, d1, d2, d3;
            d0.u = v0; d1.u = v1; d2.u = v2; d3.u = v3;
            acc0 += w4.x*(float)d0.h[0] + w4.y*(float)d1.h[0]
                  + w4.z*(float)d2.h[0] + w4.w*(float)d3.h[0];
            acc1 += w4.x*(float)d0.h[1] + w4.y*(float)d1.h[1]
                  + w4.z*(float)d2.h[1] + w4.w*(float)d3.h[1];
          }
          sm.row.ctxred[rg][col][0] = acc0;
          sm.row.ctxred[rg][col][1] = acc1;
          __syncthreads();
          if (tid < 256){
            union { h16 h[2]; unsigned u; } cv;
            cv.h[0] = (h16)(sm.row.ctxred[0][tid][0] + sm.row.ctxred[1][tid][0]);
            cv.h[1] = (h16)(sm.row.ctxred[0][tid][1] + sm.row.ctxred[1][tid][1]);
            astu32((unsigned*)(wsh + CTXF_H) + b*256 + tid, cv.u);
          }
        }
      }
    } else if (bid < 288){
      // dec-LSTM ah/dh partial (K=2048): 16 rows/block, 8 waves x 8 K-steps
      if (t < 400){
        const int n0 = (bid-32)*16;
        const int n = n0 + i16;
        f32x4 acc0 = {0,0,0,0}, acc1 = {0,0,0,0};
        const long long curO = (long long)cur*32768;
        for (int s = wv*8; s < wv*8 + 8; ++s){
          const int k0 = s*32;
          const h16* pA = (k0 < 1024) ? wsh + DWIHF_H + (long long)n*1536 + k0 + q*8
                                      : wsh + DWHHF_H + (long long)n*1024 + (k0-1024) + q*8;
          half8 A = *(const half8*)pA;
          half8 B0, B1;
          if (k0 < 1024){
            B0 = ald16(wsh + AHF_H + curO + i16*1024 + k0 + q*8);
            B1 = ald16(wsh + AHF_H + curO + (16+i16)*1024 + k0 + q*8);
          } else {
            B0 = ald16(wsh + DHF_H + i16*1024 + (k0-1024) + q*8);
            B1 = ald16(wsh + DHF_H + (16+i16)*1024 + (k0-1024) + q*8);
          }
          acc0 = MFMA16(A, B0, acc0);
          acc1 = MFMA16(A, B1, acc1);
        }
        #pragma unroll
        for (int r = 0; r < 4; ++r){
          sm.g.red[wv][0][q*4+r][i16] = acc0[r];
          sm.g.red[wv][1][q*4+r][i16] = acc1[r];
        }
        __syncthreads();
        if (tid < 256){
          const int r16 = tid & 15, c = tid >> 4;
          #pragma unroll
          for (int bt = 0; bt < 2; ++bt){
            float v = 0.f;
            #pragma unroll
            for (int w8 = 0; w8 < 8; ++w8) v += sm.g.red[w8][bt][r16][c];
            astf(ws + DPART_F + (long long)(bt*16 + c)*4096 + n0 + r16, v);
          }
        }
      }
    } else if (bid < 320){
      // mel + gate projections for step t-1; proj weights from f16 copy
      if (t >= 1){
        const int b = bid - 288;
        for (int i = tid; i < 384; i += 512){
          union { unsigned long long u; h16 h[4]; } hu;
          hu.u = (i < 256) ? aldu64(wsh + DHF_H + b*1024 + i*4)
                           : aldu64(wsh + CTXF_H + b*512 + (i-256)*4);
          #pragma unroll
          for (int j = 0; j < 4; ++j) sm.mel.hc[i*4+j] = (float)hu.h[j];
        }
        __syncthreads();
        if (tid < 320){
          const int r = tid >> 2, h4 = tid & 3;       // 80 rows x 4 K-quarters
          const h16* pr = wsh + PWF_H + (long long)r*1536 + h4*384;
          const float* hcp = &sm.mel.hc[h4*384];
          float acc = 0.f;
          for (int k = 0; k < 384; k += 8){
            half8 wq = *(const half8*)(pr + k);
            acc += (float)wq[0]*hcp[k]   + (float)wq[1]*hcp[k+1]
                 + (float)wq[2]*hcp[k+2] + (float)wq[3]*hcp[k+3]
                 + (float)wq[4]*hcp[k+4] + (float)wq[5]*hcp[k+5]
                 + (float)wq[6]*hcp[k+6] + (float)wq[7]*hcp[k+7];
          }
          sm.mel.mp[r][h4] = acc;
        } else if (tid >= 384 && tid < 448){
          const int l = tid - 384;                    // wave 6, full wave
          const float* gp  = P.gw + l*24;
          const float* hcp = &sm.mel.hc[l*24];
          float acc = 0.f;
          #pragma unroll
          for (int k = 0; k < 24; ++k) acc += gp[k]*hcp[k];
          for (int o = 32; o; o >>= 1) acc += __shfl_xor(acc, o, 64);
          if (l == 0) sm.mel.gacc = acc;
        }
        __syncthreads();
        if (tid < 80)
          P.out[((long long)b*80 + tid)*400 + (t-1)] =
            sm.mel.mp[tid][0] + sm.mel.mp[tid][1] + sm.mel.mp[tid][2] + sm.mel.mp[tid][3] + P.pb[tid];
        if (tid == 80)
          P.out[GATE0 + (long long)b*400 + (t-1)] = sm.mel.gacc + P.gb[0];
      }
    }
    gbar(bar, ++ep, false);
  }
}

extern "C" void kernel_launch(void* const* d_in, const int* in_sizes, int n_in,
                              void* d_out, int out_size, void* d_ws, size_t ws_size,
                              hipStream_t stream) {
  (void)in_sizes; (void)n_in; (void)out_size; (void)ws_size;
  Params p;
  p.memory = (const float*)d_in[0];
  p.dec_in = (const float*)d_in[1];
  p.memlen = (const int*)d_in[2];
  p.w1   = (const float*)d_in[3];
  p.w2   = (const float*)d_in[4];
  p.awih = (const float*)d_in[5];
  p.awhh = (const float*)d_in[6];
  p.abih = (const float*)d_in[7];
  p.abhh = (const float*)d_in[8];
  p.qw   = (const float*)d_in[9];
  p.mw   = (const float*)d_in[10];
  p.vw   = (const float*)d_in[11];
  p.lcw  = (const float*)d_in[12];
  p.ldw  = (const float*)d_in[13];
  p.dwih = (const float*)d_in[14];
  p.dwhh = (const float*)d_in[15];
  p.dbih = (const float*)d_in[16];
  p.dbhh = (const float*)d_in[17];
  p.pw   = (const float*)d_in[18];
  p.pb   = (const float*)d_in[19];
  p.gw   = (const float*)d_in[20];
  p.gb   = (const float*)d_in[21];
  p.out  = (float*)d_out;
  p.ws   = (float*)d_ws;

  hipLaunchKernelGGL(init_kernel, dim3(1), dim3(512), 0, stream, p.ws);
  hipLaunchKernelGGL(decoder_kernel, dim3(512), dim3(512), 0, stream, p);
}